// Round 8
// baseline (169.953 us; speedup 1.0000x reference)
//
#include <hip/hip_runtime.h>
#include <hip/hip_bf16.h>

#define M_TOK 2048
#define KDIM  4096
#define NDIM  4096
#define BM    128
#define BN    128
#define BK    64
#define NT    (KDIM / BK)          // 64 K-tiles
#define ATILE (BM * BK)            // 8192 ushorts (16 KB)

typedef __bf16 bf16x8 __attribute__((ext_vector_type(8)));
typedef float  f32x16 __attribute__((ext_vector_type(16)));
typedef short  short8 __attribute__((ext_vector_type(8)));

__device__ __forceinline__ ushort f2bf(float f) {
    union { float f; unsigned u; } v; v.f = f;
    unsigned r = (v.u + 0x7fffu + ((v.u >> 16) & 1u)) >> 16;
    return (ushort)r;
}

__device__ __forceinline__ void gload16(const ushort* g, ushort* l) {
    __builtin_amdgcn_global_load_lds(
        (const __attribute__((address_space(1))) void*)g,
        (__attribute__((address_space(3))) void*)l, 16, 0, 0);
}

// ---------------- kernel 1: cast x -> bf16  AND  build W3 (merged) ----------------
__global__ __launch_bounds__(256) void k_prep(const float* __restrict__ x,
                                              ushort* __restrict__ xb,
                                              const float* __restrict__ g0,
                                              const float* __restrict__ g1,
                                              const float* __restrict__ alpha,
                                              const float* __restrict__ pds,
                                              const int* __restrict__ iperm,
                                              const int* __restrict__ oinv,
                                              ushort* __restrict__ W3) {
    __shared__ float  G0s[1024];   // [j0][r]
    __shared__ float  G1s[1024];   // [r][j1]
    __shared__ ushort rowb[4096];
    const int b = blockIdx.x;
    if (b < 4096) {
        const int i = (b * 256 + threadIdx.x) * 8;
        float4 a = *reinterpret_cast<const float4*>(x + i);
        float4 c = *reinterpret_cast<const float4*>(x + i + 4);
        short8 o;
        o[0] = (short)f2bf(a.x); o[1] = (short)f2bf(a.y);
        o[2] = (short)f2bf(a.z); o[3] = (short)f2bf(a.w);
        o[4] = (short)f2bf(c.x); o[5] = (short)f2bf(c.y);
        o[6] = (short)f2bf(c.z); o[7] = (short)f2bf(c.w);
        *reinterpret_cast<short8*>(xb + i) = o;
        return;
    }
    const int o  = b - 4096;
    const int op = oinv[o];
    const int i0 = op >> 6, i1 = op & 63;
    const float sc = alpha[0] * pds[op];

    for (int idx = threadIdx.x; idx < 1024; idx += 256) {
        G0s[idx] = g0[i0 * 1024 + idx];
        G1s[idx] = g1[(idx >> 6) * 4096 + i1 * 64 + (idx & 63)];
    }
    __syncthreads();
    for (int jp = threadIdx.x; jp < 4096; jp += 256) {
        const int j0 = jp >> 6, j1 = jp & 63;
        float v = 0.f;
#pragma unroll
        for (int r = 0; r < 16; ++r)
            v = fmaf(G0s[j0 * 16 + r], G1s[r * 64 + j1], v);
        rowb[iperm[jp]] = f2bf(v * sc);
    }
    __syncthreads();
    for (int t = threadIdx.x; t < 512; t += 256)
        *reinterpret_cast<short8*>(W3 + (size_t)o * 4096 + t * 8) =
            *reinterpret_cast<const short8*>(rowb + t * 8);
}

// ---------------- kernel 2: C = A @ B^T + bias ----------------
// BM=BN=128, 4 waves (2M x 2N, wave tile 64x64), mfma_32x32x16.
// A staged via LDS (dbuf 32KB, R5-verified swizzle); B loaded DIRECTLY
// global->VGPR (double-buffered regs, 2 tiles ahead). Counted vmcnt(12).
// Grid 512 -> 2 blocks/CU.
__global__ __launch_bounds__(256, 2)
void k_gemm(const ushort* __restrict__ A, const ushort* __restrict__ B,
            const float* __restrict__ bias, float* __restrict__ C) {
    __shared__ __align__(16) ushort lds[2 * ATILE];   // 32 KB
    const int tid  = threadIdx.x;
    const int lane = tid & 63;
    const int w    = tid >> 6;   // 0..3
    const int wr   = w >> 1;     // 0..1 (M)
    const int wc   = w & 1;      // 0..1 (N)

    // XCD map: grid 512 = 16(by) x 32(bx); each XCD owns full-by x 4-wide bx
    // (B slab 4 cols x 128 x 4096 x 2B = 4 MB -> L2-resident per XCD)
    const int bid = blockIdx.x;
    const int xcd = bid & 7, li = bid >> 3;       // li 0..63
    const int by = li >> 2;                       // 0..15
    const int bx = xcd * 4 + (li & 3);            // 0..31
    const long brow = (long)by * BM, bcol = (long)bx * BN;

    // ---- A staging: 4 gload16/thread/tile. thread t -> row t>>3 (+32c),
    // LDS slot t&7; global slot pre-swizzled: (t&7) ^ (row&7).
    const int rowt = tid >> 3;
    const ushort* gA0 = A + (size_t)(brow + rowt) * KDIM
                          + (((tid & 7) ^ (rowt & 7)) << 3);
    const int wub = (tid & ~63) * 8;   // wave-uniform LDS base (ushorts)

    auto stageA = [&](int bufo, int kt) {
#pragma unroll
        for (int c = 0; c < 4; ++c)
            gload16(gA0 + (size_t)(c * 32) * KDIM + kt,
                    (ushort*)lds + bufo + c * 2048 + wub);
    };

    // ---- A fragment reads (32x32x16: row = lane&31 [+m*32], k = hb*8 + j)
    const int lane31 = lane & 31;
    const int hb = lane >> 5;
    int aoff[4];
#pragma unroll
    for (int kk = 0; kk < 4; ++kk)
        aoff[kk] = (wr * 64 + lane31) * 64
                 + ((kk * 16 + hb * 8) ^ ((lane & 7) * 8));

    // ---- B direct-to-reg: wave (wr,wc) cols wc*64 + n*32 + lane31
    const ushort* pB[2];
    pB[0] = B + (size_t)(bcol + wc * 64 + lane31) * KDIM + hb * 8;
    pB[1] = pB[0] + (size_t)32 * KDIM;

    bf16x8 X[2][4], Y[2][4];   // [n][kk], static-indexed only
    auto loadB = [&](bf16x8 (&R)[2][4], int kt) {
#pragma unroll
        for (int n = 0; n < 2; ++n)
#pragma unroll
            for (int kk = 0; kk < 4; ++kk)
                R[n][kk] = *reinterpret_cast<const bf16x8*>(pB[n] + kt + kk * 16);
    };

    f32x16 acc[2][2] = {};

    auto compute = [&](bf16x8 (&R)[2][4], int bufo) {
#pragma unroll
        for (int kk = 0; kk < 4; ++kk) {
            bf16x8 a0 = *reinterpret_cast<const bf16x8*>(lds + bufo + aoff[kk]);
            bf16x8 a1 = *reinterpret_cast<const bf16x8*>(lds + bufo + aoff[kk] + 2048);
            __builtin_amdgcn_s_setprio(1);
            acc[0][0] = __builtin_amdgcn_mfma_f32_32x32x16_bf16(a0, R[0][kk], acc[0][0], 0, 0, 0);
            acc[0][1] = __builtin_amdgcn_mfma_f32_32x32x16_bf16(a0, R[1][kk], acc[0][1], 0, 0, 0);
            acc[1][0] = __builtin_amdgcn_mfma_f32_32x32x16_bf16(a1, R[0][kk], acc[1][0], 0, 0, 0);
            acc[1][1] = __builtin_amdgcn_mfma_f32_32x32x16_bf16(a1, R[1][kk], acc[1][1], 0, 0, 0);
            __builtin_amdgcn_s_setprio(0);
        }
    };

#define VM12 asm volatile("s_waitcnt vmcnt(12)" ::: "memory")
#define VM0  asm volatile("s_waitcnt vmcnt(0)"  ::: "memory")
#define BAR  __builtin_amdgcn_s_barrier()

    // prologue: tiles 0,1 (A->LDS, B->regs); wait tile 0 (12 stay in flight)
    stageA(0, 0);      loadB(X, 0);
    stageA(ATILE, BK); loadB(Y, BK);
    VM12; BAR;

    for (int i = 0; i < NT / 2 - 1; ++i) {
        const int k2 = (2 * i + 2) * BK, k3 = (2 * i + 3) * BK;
        compute(X, 0);              // tile 2i  (A buf0, B regs X)
        loadB(X, k2);               // refill X (X fully consumed above)
        BAR;                        // all waves done reading A buf0
        stageA(0, k2);              // overwrite A buf0
        VM12; BAR;                  // tile 2i+1 landed (12 newer outstanding)
        compute(Y, ATILE);          // tile 2i+1
        loadB(Y, k3);
        BAR;
        stageA(ATILE, k3);
        VM12; BAR;                  // tile 2i+2 landed
    }
    compute(X, 0);                  // tile NT-2
    VM0; BAR;                       // tile NT-1 fully landed
    compute(Y, ATILE);              // tile NT-1
#undef VM12
#undef VM0
#undef BAR

    // ---- epilogue: C/D layout col = lane&31, row = (r&3) + 8*(r>>2) + 4*hb
    const int  ccol = (int)bcol + wc * 64 + lane31;
    const long row0 = brow + wr * 64 + 4 * hb;
    const float bv0 = bias[ccol];
    const float bv1 = bias[ccol + 32];
#pragma unroll
    for (int m = 0; m < 2; ++m) {
#pragma unroll
        for (int r = 0; r < 16; ++r) {
            const long row = row0 + m * 32 + (r & 3) + 8 * (r >> 2);
            C[row * NDIM + ccol]      = acc[m][0][r] + bv0;
            C[row * NDIM + ccol + 32] = acc[m][1][r] + bv1;
        }
    }
}

extern "C" void kernel_launch(void* const* d_in, const int* in_sizes, int n_in,
                              void* d_out, int out_size, void* d_ws, size_t ws_size,
                              hipStream_t stream) {
    const float* x     = (const float*)d_in[0];
    const float* g0    = (const float*)d_in[1];
    const float* g1    = (const float*)d_in[2];
    const float* alpha = (const float*)d_in[3];
    const float* pds   = (const float*)d_in[4];
    const float* bias  = (const float*)d_in[5];
    const int*   iperm = (const int*)d_in[6];
    const int*   oinv  = (const int*)d_in[7];
    float* out = (float*)d_out;

    ushort* W3 = (ushort*)d_ws;                         // 4096*4096 bf16 = 32MB
    ushort* Xb = (ushort*)d_ws + (size_t)NDIM * KDIM;   // 2048*4096 bf16 = 16MB

    hipLaunchKernelGGL(k_prep, dim3(8192), dim3(256), 0, stream,
                       x, Xb, g0, g1, alpha, pds, iperm, oinv, W3);
    hipLaunchKernelGGL(k_gemm, dim3((M_TOK / BM) * (NDIM / BN)), dim3(256), 0, stream,
                       Xb, W3, bias, out);
}

// Round 10
// 113.932 us; speedup vs baseline: 1.4917x; 1.4917x over previous
//
#include <hip/hip_runtime.h>
#include <hip/hip_bf16.h>

#define M_TOK 2048
#define KDIM  4096
#define NDIM  4096
#define BM    128
#define BN    128
#define BK    64
#define NT    (KDIM / BK)          // 64 K-tiles
#define ATILE (BM * BK)            // 8192 ushorts (16 KB)

typedef __bf16 bf16x8 __attribute__((ext_vector_type(8)));
typedef float  f32x4  __attribute__((ext_vector_type(4)));
typedef short  short8 __attribute__((ext_vector_type(8)));

__device__ __forceinline__ ushort f2bf(float f) {
    union { float f; unsigned u; } v; v.f = f;
    unsigned r = (v.u + 0x7fffu + ((v.u >> 16) & 1u)) >> 16;
    return (ushort)r;
}

__device__ __forceinline__ void gload16(const ushort* g, ushort* l) {
    __builtin_amdgcn_global_load_lds(
        (const __attribute__((address_space(1))) void*)g,
        (__attribute__((address_space(3))) void*)l, 16, 0, 0);
}

// ---------------- kernel 1: cast x -> bf16  AND  build W3f (fragment-native) ----
// W3f layout: 1KB blocks of [16 cols x 32 k]; ushort index for (o=col, j=k):
//   ((o>>4)*128 + (j>>5))*512 + ((j>>3)&3)*128 + (o&15)*8 + (j&7)
// so lane l of a frag-load holds col = c16*16 + (l&15), k = kb*32 + (l>>4)*8 + j.
__global__ __launch_bounds__(256) void k_prep(const float* __restrict__ x,
                                              ushort* __restrict__ xb,
                                              const float* __restrict__ g0,
                                              const float* __restrict__ g1,
                                              const float* __restrict__ alpha,
                                              const float* __restrict__ pds,
                                              const int* __restrict__ iperm,
                                              const int* __restrict__ oinv,
                                              ushort* __restrict__ W3f) {
    __shared__ float  G0s[1024];   // [j0][r]
    __shared__ float  G1s[1024];   // [r][j1]
    __shared__ ushort rowb[4096];
    const int b = blockIdx.x;
    if (b < 4096) {
        const int i = (b * 256 + threadIdx.x) * 8;
        float4 a = *reinterpret_cast<const float4*>(x + i);
        float4 c = *reinterpret_cast<const float4*>(x + i + 4);
        short8 o;
        o[0] = (short)f2bf(a.x); o[1] = (short)f2bf(a.y);
        o[2] = (short)f2bf(a.z); o[3] = (short)f2bf(a.w);
        o[4] = (short)f2bf(c.x); o[5] = (short)f2bf(c.y);
        o[6] = (short)f2bf(c.z); o[7] = (short)f2bf(c.w);
        *reinterpret_cast<short8*>(xb + i) = o;
        return;
    }
    const int o  = b - 4096;       // W3 row = output col index
    const int op = oinv[o];
    const int i0 = op >> 6, i1 = op & 63;
    const float sc = alpha[0] * pds[op];

    for (int idx = threadIdx.x; idx < 1024; idx += 256) {
        G0s[idx] = g0[i0 * 1024 + idx];
        G1s[idx] = g1[(idx >> 6) * 4096 + i1 * 64 + (idx & 63)];
    }
    __syncthreads();
    for (int jp = threadIdx.x; jp < 4096; jp += 256) {
        const int j0 = jp >> 6, j1 = jp & 63;
        float v = 0.f;
#pragma unroll
        for (int r = 0; r < 16; ++r)
            v = fmaf(G0s[j0 * 16 + r], G1s[r * 64 + j1], v);
        rowb[iperm[jp]] = f2bf(v * sc);
    }
    __syncthreads();
    // scatter rowb (k-ordered) into fragment-native blocks, 16B per store
    const size_t cbase = (size_t)(o >> 4) * 128 * 512 + (size_t)(o & 15) * 8;
#pragma unroll
    for (int u = 0; u < 2; ++u) {
        const int j8 = threadIdx.x * 2 + u;          // 0..511 (j = j8*8..+7)
        const size_t addr = cbase + (size_t)(j8 >> 2) * 512 + (size_t)(j8 & 3) * 128;
        *reinterpret_cast<short8*>(W3f + addr) =
            *reinterpret_cast<const short8*>(rowb + j8 * 8);
    }
}

// ---------------- kernel 2: C = A @ B^T + bias ----------------
// BM=BN=128, 4 waves (2M x 2N, wave tile 64x64), mfma_16x16x32.
// A via LDS dbuf (32KB, proven zero-conflict lane&15 pattern); B fragment-
// native from global (coalesced 1KB per instr, L1/L2-resident), X/Y reg dbuf.
// Counted vmcnt(12). Grid 512 -> 2 blocks/CU.
__global__ __launch_bounds__(256, 2)
void k_gemm(const ushort* __restrict__ A, const ushort* __restrict__ Bf,
            const float* __restrict__ bias, float* __restrict__ C) {
    __shared__ __align__(16) ushort lds[2 * ATILE];   // 32 KB
    const int tid  = threadIdx.x;
    const int lane = tid & 63;
    const int w    = tid >> 6;   // 0..3
    const int wm   = w >> 1;     // 0..1 (M)
    const int wn   = w & 1;      // 0..1 (N)

    // XCD map: grid 512 = 16(by) x 32(bx); XCD owns 4 bx x 16 by
    // (B slab 4*128 cols = 4MB L2-resident; A unique 256KB/K-tile in L2)
    const int bid = blockIdx.x;
    const int xcd = bid & 7, li = bid >> 3;   // li 0..63
    const int by = li >> 2;                   // 0..15
    const int bx = xcd * 4 + (li & 3);        // 0..31
    const long brow = (long)by * BM, bcol = (long)bx * BN;

    // ---- A staging: 4 chunks of 32 rows (2048 ushorts each); thread t ->
    // row t>>3, slot t&7, global slot pre-swizzled ^ (row&7); LDS dest linear.
    const int rowt = tid >> 3;
    const ushort* gA0 = A + (size_t)(brow + rowt) * KDIM
                          + (((tid & 7) ^ (rowt & 7)) << 3);
    const int wub = (tid & ~63) * 8;   // wave-uniform LDS base (ushorts)

    auto stageA = [&](int bufo, int kt) {
#pragma unroll
        for (int c = 0; c < 4; ++c)
            gload16(gA0 + (size_t)(c * 32) * KDIM + kt,
                    (ushort*)lds + bufo + c * 2048 + wub);   // FIX: 2048, was 4096
    };

    // ---- A fragment reads (16x16x32), R2/R5/R6/R7-proven zero-conflict
    const int lr = lane & 15;
    int colswz[2];
#pragma unroll
    for (int kk = 0; kk < 2; ++kk)
        colswz[kk] = ((kk * 4 + (lane >> 4)) ^ (lane & 7)) * 8;
    const int rowA = (wm * 64 + lr) * 64;   // + m*1024

    // ---- B fragment-native pointers: wave covers c16 = bx*8 + wn*4 + n
    const ushort* pB = Bf + (size_t)(bx * 8 + wn * 4) * 128 * 512 + lane * 8;

    bf16x8 X[4][2], Y[4][2];   // [n][kk], static indexing only
    auto loadB = [&](bf16x8 (&R)[4][2], int kt) {
        const int kb = kt >> 5;
#pragma unroll
        for (int n = 0; n < 4; ++n)
#pragma unroll
            for (int kk = 0; kk < 2; ++kk)
                R[n][kk] = *reinterpret_cast<const bf16x8*>(
                    pB + ((size_t)n * 128 + kb + kk) * 512);
    };

    f32x4 acc[4][4] = {};

    auto compute = [&](bf16x8 (&R)[4][2], int bufo) {
#pragma unroll
        for (int kk = 0; kk < 2; ++kk) {
            bf16x8 af[4];
#pragma unroll
            for (int m = 0; m < 4; ++m)
                af[m] = *reinterpret_cast<const bf16x8*>(
                    lds + bufo + rowA + m * 1024 + colswz[kk]);
            __builtin_amdgcn_s_setprio(1);
#pragma unroll
            for (int m = 0; m < 4; ++m)
#pragma unroll
                for (int n = 0; n < 4; ++n)
                    acc[m][n] = __builtin_amdgcn_mfma_f32_16x16x32_bf16(
                        af[m], R[n][kk], acc[m][n], 0, 0, 0);
            __builtin_amdgcn_s_setprio(0);
        }
    };

#define VM12 asm volatile("s_waitcnt vmcnt(12)" ::: "memory")
#define VM0  asm volatile("s_waitcnt vmcnt(0)"  ::: "memory")
#define BAR  __builtin_amdgcn_s_barrier()

    // prologue: tiles 0,1 (A->LDS, B->regs), 24 outstanding; wait tile 0
    stageA(0, 0);      loadB(X, 0);
    stageA(ATILE, BK); loadB(Y, BK);
    VM12; BAR;

    for (int i = 0; i < NT / 2 - 1; ++i) {
        const int k2 = (2 * i + 2) * BK, k3 = (2 * i + 3) * BK;
        compute(X, 0);          // tile 2i
        loadB(X, k2);           // +8
        BAR;                    // all waves done reading A buf0
        stageA(0, k2);          // +4, overwrite buf0
        VM12; BAR;              // tile 2i+1 (A buf1 + Y) landed, all waves
        compute(Y, ATILE);      // tile 2i+1
        loadB(Y, k3);
        BAR;
        stageA(ATILE, k3);
        VM12; BAR;              // tile 2i+2 landed
    }
    compute(X, 0);              // tile NT-2
    VM0; BAR;                   // tile NT-1 (A buf1 + Y) fully landed
    compute(Y, ATILE);          // tile NT-1
#undef VM12
#undef VM0
#undef BAR

    // ---- epilogue: C/D layout col = lane&15, row = (lane>>4)*4 + v
    const int orow = (lane >> 4) * 4;
    float bv[4];
#pragma unroll
    for (int n = 0; n < 4; ++n) bv[n] = bias[bcol + wn * 64 + n * 16 + lr];
#pragma unroll
    for (int m = 0; m < 4; ++m) {
#pragma unroll
        for (int v = 0; v < 4; ++v) {
            const long grow = brow + wm * 64 + m * 16 + orow + v;
            float* cp = C + grow * NDIM + bcol + wn * 64 + lr;
#pragma unroll
            for (int n = 0; n < 4; ++n)
                cp[n * 16] = acc[m][n][v] + bv[n];
        }
    }
}

extern "C" void kernel_launch(void* const* d_in, const int* in_sizes, int n_in,
                              void* d_out, int out_size, void* d_ws, size_t ws_size,
                              hipStream_t stream) {
    const float* x     = (const float*)d_in[0];
    const float* g0    = (const float*)d_in[1];
    const float* g1    = (const float*)d_in[2];
    const float* alpha = (const float*)d_in[3];
    const float* pds   = (const float*)d_in[4];
    const float* bias  = (const float*)d_in[5];
    const int*   iperm = (const int*)d_in[6];
    const int*   oinv  = (const int*)d_in[7];
    float* out = (float*)d_out;

    ushort* W3f = (ushort*)d_ws;                        // 32MB fragment-native
    ushort* Xb  = (ushort*)d_ws + (size_t)NDIM * KDIM;  // 16MB bf16 A

    hipLaunchKernelGGL(k_prep, dim3(8192), dim3(256), 0, stream,
                       x, Xb, g0, g1, alpha, pds, iperm, oinv, W3f);
    hipLaunchKernelGGL(k_gemm, dim3((M_TOK / BM) * (NDIM / BN)), dim3(256), 0, stream,
                       Xb, W3f, bias, out);
}

// Round 11
// 111.831 us; speedup vs baseline: 1.5197x; 1.0188x over previous
//
#include <hip/hip_runtime.h>
#include <hip/hip_bf16.h>

#define M_TOK 2048
#define KDIM  4096
#define NDIM  4096
#define BM    128
#define BN    256
#define BK    64
#define NT    (KDIM / BK)          // 64 K-tiles
#define ATILE (BM * BK)            // 8192 ushorts (16 KB)

typedef __bf16 bf16x8 __attribute__((ext_vector_type(8)));
typedef float  f32x4  __attribute__((ext_vector_type(4)));
typedef short  short8 __attribute__((ext_vector_type(8)));

__device__ __forceinline__ ushort f2bf(float f) {
    union { float f; unsigned u; } v; v.f = f;
    unsigned r = (v.u + 0x7fffu + ((v.u >> 16) & 1u)) >> 16;
    return (ushort)r;
}

__device__ __forceinline__ void gload16(const ushort* g, ushort* l) {
    __builtin_amdgcn_global_load_lds(
        (const __attribute__((address_space(1))) void*)g,
        (__attribute__((address_space(3))) void*)l, 16, 0, 0);
}

// ---------------- kernel 1: cast x -> bf16  AND  build W3f (fragment-native) ----
// W3f layout: 1KB blocks of [16 cols x 32 k]; ushort index for (o=col, j=k):
//   ((o>>4)*128 + (j>>5))*512 + ((j>>3)&3)*128 + (o&15)*8 + (j&7)
__global__ __launch_bounds__(256) void k_prep(const float* __restrict__ x,
                                              ushort* __restrict__ xb,
                                              const float* __restrict__ g0,
                                              const float* __restrict__ g1,
                                              const float* __restrict__ alpha,
                                              const float* __restrict__ pds,
                                              const int* __restrict__ iperm,
                                              const int* __restrict__ oinv,
                                              ushort* __restrict__ W3f) {
    __shared__ float  G0s[1024];   // [j0][r]
    __shared__ float  G1s[1024];   // [r][j1]
    __shared__ ushort rowb[4096];
    const int b = blockIdx.x;
    if (b < 4096) {
        const int i = (b * 256 + threadIdx.x) * 8;
        float4 a = *reinterpret_cast<const float4*>(x + i);
        float4 c = *reinterpret_cast<const float4*>(x + i + 4);
        short8 o;
        o[0] = (short)f2bf(a.x); o[1] = (short)f2bf(a.y);
        o[2] = (short)f2bf(a.z); o[3] = (short)f2bf(a.w);
        o[4] = (short)f2bf(c.x); o[5] = (short)f2bf(c.y);
        o[6] = (short)f2bf(c.z); o[7] = (short)f2bf(c.w);
        *reinterpret_cast<short8*>(xb + i) = o;
        return;
    }
    const int o  = b - 4096;       // W3 row = output col index
    const int op = oinv[o];
    const int i0 = op >> 6, i1 = op & 63;
    const float sc = alpha[0] * pds[op];

    for (int idx = threadIdx.x; idx < 1024; idx += 256) {
        G0s[idx] = g0[i0 * 1024 + idx];
        G1s[idx] = g1[(idx >> 6) * 4096 + i1 * 64 + (idx & 63)];
    }
    __syncthreads();

    // per-thread: j1 = tid&63 is FIXED across s (256 ≡ 0 mod 64)
    float g1c[16];
#pragma unroll
    for (int r = 0; r < 16; ++r) g1c[r] = G1s[r * 64 + (threadIdx.x & 63)];

#pragma unroll 4
    for (int s = 0; s < 16; ++s) {
        const int jp = threadIdx.x + s * 256;
        const int j0 = jp >> 6;                 // wave-uniform per s
        const float4 q0 = *reinterpret_cast<const float4*>(&G0s[j0 * 16]);
        const float4 q1 = *reinterpret_cast<const float4*>(&G0s[j0 * 16 + 4]);
        const float4 q2 = *reinterpret_cast<const float4*>(&G0s[j0 * 16 + 8]);
        const float4 q3 = *reinterpret_cast<const float4*>(&G0s[j0 * 16 + 12]);
        float v = 0.f;
        v = fmaf(q0.x, g1c[0], v);  v = fmaf(q0.y, g1c[1], v);
        v = fmaf(q0.z, g1c[2], v);  v = fmaf(q0.w, g1c[3], v);
        v = fmaf(q1.x, g1c[4], v);  v = fmaf(q1.y, g1c[5], v);
        v = fmaf(q1.z, g1c[6], v);  v = fmaf(q1.w, g1c[7], v);
        v = fmaf(q2.x, g1c[8], v);  v = fmaf(q2.y, g1c[9], v);
        v = fmaf(q2.z, g1c[10], v); v = fmaf(q2.w, g1c[11], v);
        v = fmaf(q3.x, g1c[12], v); v = fmaf(q3.y, g1c[13], v);
        v = fmaf(q3.z, g1c[14], v); v = fmaf(q3.w, g1c[15], v);
        rowb[iperm[jp]] = f2bf(v * sc);
    }
    __syncthreads();
    // scatter rowb (k-ordered) into fragment-native blocks, 16B per store
    const size_t cbase = (size_t)(o >> 4) * 128 * 512 + (size_t)(o & 15) * 8;
#pragma unroll
    for (int u = 0; u < 2; ++u) {
        const int j8 = threadIdx.x * 2 + u;          // 0..511
        const size_t addr = cbase + (size_t)(j8 >> 2) * 512 + (size_t)(j8 & 3) * 128;
        *reinterpret_cast<short8*>(W3f + addr) =
            *reinterpret_cast<const short8*>(rowb + j8 * 8);
    }
}

// ---------------- kernel 2: C = A @ B^T + bias ----------------
// BM=128 x BN=256, 512 thr = 8 waves (2wm x 4wn, wave tile 64x64), 16x16x32.
// A via LDS dbuf (32KB, proven zero-conflict pattern); B fragment-native
// from global (coalesced 1KB loads, L2-resident), X/Y reg dbuf with B-refill
// interleaved INSIDE the MFMA phases. Counted vmcnt(10). Grid 256 (16x16).
__global__ __launch_bounds__(512, 2)
void k_gemm(const ushort* __restrict__ A, const ushort* __restrict__ Bf,
            const float* __restrict__ bias, float* __restrict__ C) {
    __shared__ __align__(16) ushort lds[2 * ATILE];   // 32 KB
    const int tid  = threadIdx.x;
    const int lane = tid & 63;
    const int w    = tid >> 6;   // 0..7
    const int wm   = w >> 2;     // 0..1 (M)
    const int wn   = w & 3;      // 0..3 (N)

    // XCD map: 256 blocks = 16(by) x 16(bx); XCD owns 2 bx x 16 by
    // (B slab 2 x 2MB = 4MB L2-resident per XCD)
    const int bid = blockIdx.x;
    const int xcd = bid & 7, li = bid >> 3;   // li 0..31
    const int by = li >> 1;                   // 0..15
    const int bx = xcd * 2 + (li & 1);        // 0..15
    const long brow = (long)by * BM, bcol = (long)bx * BN;

    // ---- A staging: 2 sweeps of 64 rows; thread t -> row t>>3, slot t&7,
    // global slot pre-swizzled ^ (row&7); LDS dest linear.
    const int rowt = tid >> 3;                // 0..63
    const ushort* gA0 = A + (size_t)(brow + rowt) * KDIM
                          + (((tid & 7) ^ (rowt & 7)) << 3);
    const int wub = (tid & ~63) * 8;          // wave-uniform LDS base

    auto stageA = [&](int bufo, int kt) {
        gload16(gA0 + kt,                     (ushort*)lds + bufo + wub);
        gload16(gA0 + (size_t)64 * KDIM + kt, (ushort*)lds + bufo + 4096 + wub);
    };

    // ---- A fragment reads (16x16x32), proven zero-conflict
    const int lr = lane & 15;
    int colswz[2];
#pragma unroll
    for (int kk = 0; kk < 2; ++kk)
        colswz[kk] = ((kk * 4 + (lane >> 4)) ^ (lane & 7)) * 8;
    const int rowA = (wm * 64 + lr) * 64;     // + m*1024

    // ---- B fragment-native: wave covers c16 = bx*16 + wn*4 + n
    const ushort* pB = Bf + (size_t)(bx * 16 + wn * 4) * 128 * 512 + lane * 8;

    bf16x8 X[4][2], Y[4][2];   // [n][kk], static indexing only
    auto loadB = [&](bf16x8 (&R)[4][2], int kt) {
        const int kb = kt >> 5;
#pragma unroll
        for (int n = 0; n < 4; ++n)
#pragma unroll
            for (int kk = 0; kk < 2; ++kk)
                R[n][kk] = *reinterpret_cast<const bf16x8*>(
                    pB + ((size_t)n * 128 + kb + kk) * 512);
    };

    f32x4 acc[4][4] = {};

#define VM10   asm volatile("s_waitcnt vmcnt(10)" ::: "memory")
#define VM0    asm volatile("s_waitcnt vmcnt(0)"  ::: "memory")
#define MEMBAR asm volatile("" ::: "memory")
#define BAR    __builtin_amdgcn_s_barrier()

    // COMPUTE_TILE: consume tile in (R, BUFO); if PF, refill R[.][kk] for
    // tile at KT right after its last MFMA consumer (in-phase overlap).
#define COMPUTE_TILE(R, BUFO, PF, KT)                                        \
    do {                                                                     \
        const int kb_ = (KT) >> 5;                                           \
        _Pragma("unroll") for (int kk = 0; kk < 2; ++kk) {                   \
            bf16x8 af[4];                                                    \
            _Pragma("unroll") for (int m = 0; m < 4; ++m)                    \
                af[m] = *reinterpret_cast<const bf16x8*>(                    \
                    lds + (BUFO) + rowA + m * 1024 + colswz[kk]);            \
            __builtin_amdgcn_s_setprio(1);                                   \
            _Pragma("unroll") for (int m = 0; m < 4; ++m)                    \
                _Pragma("unroll") for (int n = 0; n < 4; ++n)                \
                    acc[m][n] = __builtin_amdgcn_mfma_f32_16x16x32_bf16(     \
                        af[m], R[n][kk], acc[m][n], 0, 0, 0);                \
            __builtin_amdgcn_s_setprio(0);                                   \
            if (PF) {                                                        \
                _Pragma("unroll") for (int n = 0; n < 4; ++n)                \
                    R[n][kk] = *reinterpret_cast<const bf16x8*>(             \
                        pB + ((size_t)n * 128 + kb_ + kk) * 512);            \
            }                                                                \
        }                                                                    \
    } while (0)

    // prologue: tiles 0,1 (A->LDS + B->regs = 10 loads each); wait tile 0
    stageA(0, 0);        loadB(X, 0);
    stageA(ATILE, BK);   loadB(Y, BK);
    VM10; MEMBAR; BAR; MEMBAR;

    for (int i = 0; i < NT / 2 - 1; ++i) {
        const int k2 = (2 * i + 2) * BK, k3 = (2 * i + 3) * BK;
        COMPUTE_TILE(X, 0, 1, k2);       // tile 2i; refill X with B of 2i+2
        MEMBAR; BAR; MEMBAR;             // all waves done reading A buf0
        stageA(0, k2);                   // A of 2i+2 -> buf0
        VM10; MEMBAR; BAR; MEMBAR;       // tile 2i+1 landed everywhere
        COMPUTE_TILE(Y, ATILE, 1, k3);   // tile 2i+1; refill Y with B of 2i+3
        MEMBAR; BAR; MEMBAR;
        stageA(ATILE, k3);               // A of 2i+3 -> buf1
        VM10; MEMBAR; BAR; MEMBAR;       // tile 2i+2 landed everywhere
    }
    COMPUTE_TILE(X, 0, 0, 0);            // tile NT-2
    VM0; MEMBAR; BAR; MEMBAR;            // tile NT-1 fully landed
    COMPUTE_TILE(Y, ATILE, 0, 0);        // tile NT-1
#undef COMPUTE_TILE
#undef VM10
#undef VM0
#undef MEMBAR
#undef BAR

    // ---- epilogue: C/D layout col = lane&15, row = (lane>>4)*4 + v
    const int orow = (lane >> 4) * 4;
    float bv[4];
#pragma unroll
    for (int n = 0; n < 4; ++n) bv[n] = bias[bcol + wn * 64 + n * 16 + lr];
#pragma unroll
    for (int m = 0; m < 4; ++m) {
#pragma unroll
        for (int v = 0; v < 4; ++v) {
            const long grow = brow + wm * 64 + m * 16 + orow + v;
            float* cp = C + grow * NDIM + bcol + wn * 64 + lr;
#pragma unroll
            for (int n = 0; n < 4; ++n)
                cp[n * 16] = acc[m][n][v] + bv[n];
        }
    }
}

extern "C" void kernel_launch(void* const* d_in, const int* in_sizes, int n_in,
                              void* d_out, int out_size, void* d_ws, size_t ws_size,
                              hipStream_t stream) {
    const float* x     = (const float*)d_in[0];
    const float* g0    = (const float*)d_in[1];
    const float* g1    = (const float*)d_in[2];
    const float* alpha = (const float*)d_in[3];
    const float* pds   = (const float*)d_in[4];
    const float* bias  = (const float*)d_in[5];
    const int*   iperm = (const int*)d_in[6];
    const int*   oinv  = (const int*)d_in[7];
    float* out = (float*)d_out;

    ushort* W3f = (ushort*)d_ws;                        // 32MB fragment-native
    ushort* Xb  = (ushort*)d_ws + (size_t)NDIM * KDIM;  // 16MB bf16 A

    hipLaunchKernelGGL(k_prep, dim3(8192), dim3(256), 0, stream,
                       x, Xb, g0, g1, alpha, pds, iperm, oinv, W3f);
    hipLaunchKernelGGL(k_gemm, dim3((M_TOK / BM) * (NDIM / BN)), dim3(512), 0, stream,
                       Xb, W3f, bias, out);
}

// Round 12
// 100.916 us; speedup vs baseline: 1.6841x; 1.1082x over previous
//
#include <hip/hip_runtime.h>
#include <hip/hip_bf16.h>

#define M_TOK 2048
#define KDIM  4096
#define NDIM  4096
#define BM    128
#define BN    256
#define BK    64
#define NT    (KDIM / BK)          // 64 K-tiles
#define AREG  (BM * BK)            // 8192 ushorts (16 KB)
#define BREG  (BN * BK)            // 16384 ushorts (32 KB)
#define BUFSZ (AREG + BREG)        // 24576 ushorts (48 KB)

typedef __bf16 bf16x8 __attribute__((ext_vector_type(8)));
typedef float  f32x4  __attribute__((ext_vector_type(4)));
typedef short  short8 __attribute__((ext_vector_type(8)));

__device__ __forceinline__ ushort f2bf(float f) {
    union { float f; unsigned u; } v; v.f = f;
    unsigned r = (v.u + 0x7fffu + ((v.u >> 16) & 1u)) >> 16;
    return (ushort)r;
}

__device__ __forceinline__ void gload16(const ushort* g, ushort* l) {
    __builtin_amdgcn_global_load_lds(
        (const __attribute__((address_space(1))) void*)g,
        (__attribute__((address_space(3))) void*)l, 16, 0, 0);
}

// ---------------- kernel 1: cast x -> bf16  AND  build W3 row-major (merged) ----
__global__ __launch_bounds__(256) void k_prep(const float* __restrict__ x,
                                              ushort* __restrict__ xb,
                                              const float* __restrict__ g0,
                                              const float* __restrict__ g1,
                                              const float* __restrict__ alpha,
                                              const float* __restrict__ pds,
                                              const int* __restrict__ iperm,
                                              const int* __restrict__ oinv,
                                              ushort* __restrict__ W3) {
    __shared__ float  G0s[1024];   // [j0][r]
    __shared__ float  G1s[1024];   // [r][j1]
    __shared__ ushort rowb[4096];
    const int b = blockIdx.x;
    if (b < 4096) {
        const int i = (b * 256 + threadIdx.x) * 8;
        float4 a = *reinterpret_cast<const float4*>(x + i);
        float4 c = *reinterpret_cast<const float4*>(x + i + 4);
        short8 o;
        o[0] = (short)f2bf(a.x); o[1] = (short)f2bf(a.y);
        o[2] = (short)f2bf(a.z); o[3] = (short)f2bf(a.w);
        o[4] = (short)f2bf(c.x); o[5] = (short)f2bf(c.y);
        o[6] = (short)f2bf(c.z); o[7] = (short)f2bf(c.w);
        *reinterpret_cast<short8*>(xb + i) = o;
        return;
    }
    const int o  = b - 4096;       // W3 row = output col index
    const int op = oinv[o];
    const int i0 = op >> 6, i1 = op & 63;
    const float sc = alpha[0] * pds[op];

    for (int idx = threadIdx.x; idx < 1024; idx += 256) {
        G0s[idx] = g0[i0 * 1024 + idx];
        G1s[idx] = g1[(idx >> 6) * 4096 + i1 * 64 + (idx & 63)];
    }
    __syncthreads();

    // j1 = tid&63 fixed across s (256 ≡ 0 mod 64): hoist G1 column to regs
    float g1c[16];
#pragma unroll
    for (int r = 0; r < 16; ++r) g1c[r] = G1s[r * 64 + (threadIdx.x & 63)];

#pragma unroll 4
    for (int s = 0; s < 16; ++s) {
        const int jp = threadIdx.x + s * 256;
        const int j0 = jp >> 6;                 // wave-uniform per s
        const float4 q0 = *reinterpret_cast<const float4*>(&G0s[j0 * 16]);
        const float4 q1 = *reinterpret_cast<const float4*>(&G0s[j0 * 16 + 4]);
        const float4 q2 = *reinterpret_cast<const float4*>(&G0s[j0 * 16 + 8]);
        const float4 q3 = *reinterpret_cast<const float4*>(&G0s[j0 * 16 + 12]);
        float v = 0.f;
        v = fmaf(q0.x, g1c[0], v);  v = fmaf(q0.y, g1c[1], v);
        v = fmaf(q0.z, g1c[2], v);  v = fmaf(q0.w, g1c[3], v);
        v = fmaf(q1.x, g1c[4], v);  v = fmaf(q1.y, g1c[5], v);
        v = fmaf(q1.z, g1c[6], v);  v = fmaf(q1.w, g1c[7], v);
        v = fmaf(q2.x, g1c[8], v);  v = fmaf(q2.y, g1c[9], v);
        v = fmaf(q2.z, g1c[10], v); v = fmaf(q2.w, g1c[11], v);
        v = fmaf(q3.x, g1c[12], v); v = fmaf(q3.y, g1c[13], v);
        v = fmaf(q3.z, g1c[14], v); v = fmaf(q3.w, g1c[15], v);
        rowb[iperm[jp]] = f2bf(v * sc);
    }
    __syncthreads();
    // coalesced row-major store: 512 x short8, 2 per thread
#pragma unroll
    for (int u = 0; u < 2; ++u) {
        const int t = threadIdx.x + u * 256;
        *reinterpret_cast<short8*>(W3 + (size_t)o * 4096 + t * 8) =
            *reinterpret_cast<const short8*>(rowb + t * 8);
    }
}

// ---------------- kernel 2: C = A @ B^T + bias ----------------
// BM=128 x BN=256, 512 thr (8 waves 2M x 4N, wave tile 64x64), 16x16x32 MFMA.
// 3-buffer LDS ring (144KB), 2 phases/K-tile m201-style:
//   {12|4 ds_read -> 3 gload_lds -> barrier -> lgkmcnt(0) -> setprio+16 MFMA -> barrier}
// bf-frags held in regs across both phases; vmcnt(6) once per tile (2-deep).
// Proven zero-conflict swizzle (byte ^= (row&7)<<4, 128B rows). Grid 256.
__global__ __launch_bounds__(512, 1)
void k_gemm(const ushort* __restrict__ A, const ushort* __restrict__ Bw,
            const float* __restrict__ bias, float* __restrict__ C) {
    __shared__ __align__(16) ushort lds[3 * BUFSZ];   // 144 KB
    const int tid  = threadIdx.x;
    const int lane = tid & 63;
    const int w    = tid >> 6;   // 0..7
    const int wm   = w >> 2;     // 0..1 (M)
    const int wn   = w & 3;      // 0..3 (N)

    // XCD map: 256 blocks = 16(by) x 16(bx); XCD owns 2 bx x 16 by
    const int bid = blockIdx.x;
    const int xcd = bid & 7, li = bid >> 3;   // li 0..31
    const int by = li >> 1;                   // 0..15
    const int bx = xcd * 2 + (li & 1);        // 0..15
    const long brow = (long)by * BM, bcol = (long)bx * BN;

    // ---- staging: A 2 + B 4 gloads/thread/tile (64-row chunks of 8KB).
    // thread t -> row t>>3, slot t&7; global slot pre-swizzled ^ (row&7).
    const int rowt = tid >> 3;                // 0..63
    const int scol = ((tid & 7) ^ (rowt & 7)) << 3;
    const ushort* gA0 = A  + (size_t)(brow + rowt) * KDIM + scol;
    const ushort* gB0 = Bw + (size_t)(bcol + rowt) * KDIM + scol;
    const int wub = (tid & ~63) * 8;          // wave-uniform LDS base

    auto stA = [&](int sbo, int kt, int s) {
        gload16(gA0 + (size_t)(s * 64) * KDIM + kt,
                (ushort*)lds + sbo + s * 4096 + wub);
    };
    auto stB = [&](int sbo, int kt, int q) {
        gload16(gB0 + (size_t)(q * 64) * KDIM + kt,
                (ushort*)lds + sbo + AREG + q * 4096 + wub);
    };

    // ---- fragment reads (proven zero-conflict pattern)
    const int lr = lane & 15;
    int colswz[2];
#pragma unroll
    for (int kk = 0; kk < 2; ++kk)
        colswz[kk] = ((kk * 4 + (lane >> 4)) ^ (lane & 7)) * 8;
    const int rowA = (wm * 64 + lr) * 64;     // + m*1024
    const int rowB = (wn * 64 + lr) * 64;     // + n*1024 (B region)

    f32x4  acc[4][4] = {};
    bf16x8 bf[4][2];                          // held across phases

#define BARRIER do { asm volatile("" ::: "memory"); \
                     __builtin_amdgcn_s_barrier();  \
                     asm volatile("" ::: "memory"); } while (0)
#define LGKM0   asm volatile("s_waitcnt lgkmcnt(0)" ::: "memory")

    auto phaseA = [&](int bufo, int sbo, int kts, bool st) {
        bf16x8 af[2][2];
#pragma unroll
        for (int m = 0; m < 2; ++m)
#pragma unroll
            for (int kk = 0; kk < 2; ++kk)
                af[m][kk] = *reinterpret_cast<const bf16x8*>(
                    lds + bufo + rowA + m * 1024 + colswz[kk]);
#pragma unroll
        for (int n = 0; n < 4; ++n)
#pragma unroll
            for (int kk = 0; kk < 2; ++kk)
                bf[n][kk] = *reinterpret_cast<const bf16x8*>(
                    lds + bufo + AREG + rowB + n * 1024 + colswz[kk]);
        if (st) { stA(sbo, kts, 0); stA(sbo, kts, 1); stB(sbo, kts, 0); }
        BARRIER;
        LGKM0;
        __builtin_amdgcn_s_setprio(1);
#pragma unroll
        for (int kk = 0; kk < 2; ++kk)
#pragma unroll
            for (int m = 0; m < 2; ++m)
#pragma unroll
                for (int n = 0; n < 4; ++n)
                    acc[m][n] = __builtin_amdgcn_mfma_f32_16x16x32_bf16(
                        af[m][kk], bf[n][kk], acc[m][n], 0, 0, 0);
        __builtin_amdgcn_s_setprio(0);
        BARRIER;
    };

    auto phaseB = [&](int bufo, int sbo, int kts, bool st, int vmN) {
        bf16x8 af[2][2];
#pragma unroll
        for (int m = 0; m < 2; ++m)
#pragma unroll
            for (int kk = 0; kk < 2; ++kk)
                af[m][kk] = *reinterpret_cast<const bf16x8*>(
                    lds + bufo + rowA + (m + 2) * 1024 + colswz[kk]);
        if (st) { stB(sbo, kts, 1); stB(sbo, kts, 2); stB(sbo, kts, 3); }
        BARRIER;
        LGKM0;
        __builtin_amdgcn_s_setprio(1);
#pragma unroll
        for (int kk = 0; kk < 2; ++kk)
#pragma unroll
            for (int m = 0; m < 2; ++m)
#pragma unroll
                for (int n = 0; n < 4; ++n)
                    acc[m + 2][n] = __builtin_amdgcn_mfma_f32_16x16x32_bf16(
                        af[m][kk], bf[n][kk], acc[m + 2][n], 0, 0, 0);
        __builtin_amdgcn_s_setprio(0);
        if (vmN == 6)      asm volatile("s_waitcnt vmcnt(6)" ::: "memory");
        else if (vmN == 0) asm volatile("s_waitcnt vmcnt(0)" ::: "memory");
        BARRIER;
    };

    // prologue: tile 0 -> buf0, tile 1 -> buf1 (12 loads); wait tile 0
#pragma unroll
    for (int s = 0; s < 2; ++s) stA(0, 0, s);
#pragma unroll
    for (int q = 0; q < 4; ++q) stB(0, 0, q);
#pragma unroll
    for (int s = 0; s < 2; ++s) stA(BUFSZ, BK, s);
#pragma unroll
    for (int q = 0; q < 4; ++q) stB(BUFSZ, BK, q);
    asm volatile("s_waitcnt vmcnt(6)" ::: "memory");
    BARRIER;

    int cur = 0, nxt = BUFSZ, stg = 2 * BUFSZ;
    for (int g = 0; g < NT - 2; ++g) {        // g = 0..61
        const int kts = (g + 2) * BK;
        phaseA(cur, stg, kts, true);
        phaseB(cur, stg, kts, true, 6);       // t(g+1) landed after this
        const int t = cur; cur = nxt; nxt = stg; stg = t;
    }
    // tile 62: no staging; drain tile 63's loads
    phaseA(cur, 0, 0, false);
    phaseB(cur, 0, 0, false, 0);
    { const int t = cur; cur = nxt; nxt = stg; stg = t; }
    // tile 63
    phaseA(cur, 0, 0, false);
    phaseB(cur, 0, 0, false, -1);

#undef BARRIER
#undef LGKM0

    // ---- epilogue: C/D layout col = lane&15, row = (lane>>4)*4 + v
    const int orow = (lane >> 4) * 4;
    float bv[4];
#pragma unroll
    for (int n = 0; n < 4; ++n) bv[n] = bias[bcol + wn * 64 + n * 16 + lr];
#pragma unroll
    for (int m = 0; m < 4; ++m) {
#pragma unroll
        for (int v = 0; v < 4; ++v) {
            const long grow = brow + wm * 64 + m * 16 + orow + v;
            float* cp = C + grow * NDIM + bcol + wn * 64 + lr;
#pragma unroll
            for (int n = 0; n < 4; ++n)
                cp[n * 16] = acc[m][n][v] + bv[n];
        }
    }
}

extern "C" void kernel_launch(void* const* d_in, const int* in_sizes, int n_in,
                              void* d_out, int out_size, void* d_ws, size_t ws_size,
                              hipStream_t stream) {
    const float* x     = (const float*)d_in[0];
    const float* g0    = (const float*)d_in[1];
    const float* g1    = (const float*)d_in[2];
    const float* alpha = (const float*)d_in[3];
    const float* pds   = (const float*)d_in[4];
    const float* bias  = (const float*)d_in[5];
    const int*   iperm = (const int*)d_in[6];
    const int*   oinv  = (const int*)d_in[7];
    float* out = (float*)d_out;

    ushort* W3 = (ushort*)d_ws;                         // 4096*4096 bf16 = 32MB
    ushort* Xb = (ushort*)d_ws + (size_t)NDIM * KDIM;   // 2048*4096 bf16 = 16MB

    hipLaunchKernelGGL(k_prep, dim3(8192), dim3(256), 0, stream,
                       x, Xb, g0, g1, alpha, pds, iperm, oinv, W3);
    hipLaunchKernelGGL(k_gemm, dim3((M_TOK / BM) * (NDIM / BN)), dim3(512), 0, stream,
                       Xb, W3, bias, out);
}